// Round 1
// baseline (265.299 us; speedup 1.0000x reference)
//
#include <hip/hip_runtime.h>
#include <hip/hip_bf16.h>
#include <math.h>

// Problem constants (from reference)
#define NATOMS 262144
#define NGRAPH 4096
#define DIM    512
#define VOC    100

// Workspace layout (bytes):
//   hist   int32 [NGRAPH][VOC]  @ 0                     = 1,638,400
//   possum f32   [NGRAPH][3]    @ 1,638,400             =    49,152
//   cnt    int32 [NGRAPH]       @ 1,687,552             =    16,384
//   M1     f32   [103][512]     @ 1,703,936             =   210,944
// total ~1.87 MB

__device__ __forceinline__ float gelu_tanh(float x) {
    // jax.nn.gelu default approximate=True (tanh form)
    const float c = 0.7978845608028654f; // sqrt(2/pi)
    float x3 = x * x * x;
    return 0.5f * x * (1.0f + tanhf(c * (x + 0.044715f * x3)));
}

// Per-atom accumulation: histogram of atomic numbers, position sums, counts.
// batch is SORTED, so most waves are graph-uniform -> 1 atomic per wave for
// pos/count instead of 64.
__global__ void k_accum(const int* __restrict__ an, const float* __restrict__ pos,
                        const int* __restrict__ batch,
                        int* __restrict__ hist, float* __restrict__ possum,
                        int* __restrict__ cnt, int n) {
    int i = blockIdx.x * blockDim.x + threadIdx.x;
    if (i >= n) return;                 // n % 64 == 0, so no partial waves
    int g = batch[i];
    int v = an[i];
    float px = pos[3 * i + 0];
    float py = pos[3 * i + 1];
    float pz = pos[3 * i + 2];

    atomicAdd(&hist[g * VOC + v], 1);   // different v per lane: low contention

    int lane = threadIdx.x & 63;
    int gFirst = __shfl(g, 0);
    int gLast  = __shfl(g, 63);
    if (gFirst == gLast) {
        // whole wave in one graph (sorted batch): tree-reduce, single atomic
        float sx = px, sy = py, sz = pz;
        #pragma unroll
        for (int off = 32; off; off >>= 1) {
            sx += __shfl_down(sx, off);
            sy += __shfl_down(sy, off);
            sz += __shfl_down(sz, off);
        }
        if (lane == 0) {
            atomicAdd(&possum[g * 3 + 0], sx);
            atomicAdd(&possum[g * 3 + 1], sy);
            atomicAdd(&possum[g * 3 + 2], sz);
            atomicAdd(&cnt[g], 64);
        }
    } else {
        atomicAdd(&possum[g * 3 + 0], px);
        atomicAdd(&possum[g * 3 + 1], py);
        atomicAdd(&possum[g * 3 + 2], pz);
        atomicAdd(&cnt[g], 1);
    }
}

// M1[103][512] = concat(embed[100][512], w_pos[3][512]) @ w1[512][512]
// Tile: 8 source rows x 128 output cols per block; src rows staged in LDS,
// w1 reads coalesced (w1 is 1MB -> L2 resident).
__global__ void k_mat(const float* __restrict__ embed, const float* __restrict__ w_pos,
                      const float* __restrict__ w1, float* __restrict__ M1) {
    int rt = blockIdx.x;           // 0..12 (row tile of 8)
    int jc = blockIdx.y;           // 0..3  (col chunk of 128)
    int t  = threadIdx.x;          // 0..127
    int j  = jc * 128 + t;
    int r0 = rt * 8;

    __shared__ float src[8][DIM];  // 16 KB
    for (int idx = t; idx < 8 * DIM; idx += 128) {
        int rr = idx >> 9;
        int k  = idx & (DIM - 1);
        int r  = r0 + rr;
        float val = 0.0f;
        if (r < VOC)          val = embed[r * DIM + k];
        else if (r < VOC + 3) val = w_pos[(r - VOC) * DIM + k];
        src[rr][k] = val;
    }
    __syncthreads();

    float acc[8];
    #pragma unroll
    for (int rr = 0; rr < 8; rr++) acc[rr] = 0.0f;

    #pragma unroll 4
    for (int k = 0; k < DIM; k++) {
        float w = w1[k * DIM + j];          // coalesced across threads
        #pragma unroll
        for (int rr = 0; rr < 8; rr++)
            acc[rr] = fmaf(src[rr][k], w, acc[rr]);  // src broadcast from LDS
    }

    #pragma unroll
    for (int rr = 0; rr < 8; rr++) {
        int r = r0 + rr;
        if (r < VOC + 3) M1[r * DIM + j] = acc[rr];
    }
}

// Final: per graph g: pre[j] = (hist[g]·M1[:,j]) / cnt + b1[j];
// energy[g] = sum_j gelu(pre[j]) * w2[j] + b2.
// 16 graphs per block, 512 threads (thread j owns output dim j).
__global__ void k_final(const int* __restrict__ hist, const float* __restrict__ possum,
                        const int* __restrict__ cnt, const float* __restrict__ M1,
                        const float* __restrict__ b1, const float* __restrict__ w2,
                        const float* __restrict__ b2, float* __restrict__ out, int G) {
    const int G0 = blockIdx.x * 16;
    const int j = threadIdx.x;                 // 0..511

    __shared__ float hl[16][104];              // [u][0..99]=hist, [100..102]=possum, [103]=count
    __shared__ float part[8][16];              // per-wave partials

    for (int idx = j; idx < 16 * 104; idx += 512) {
        int u = idx / 104;
        int c = idx - u * 104;
        int g = G0 + u;
        if (g >= G) g = G - 1;                 // safe dup (stores guarded below)
        float val;
        if (c < VOC)          val = (float)hist[g * VOC + c];
        else if (c < VOC + 3) val = possum[g * 3 + (c - VOC)];
        else                  val = (float)max(cnt[g], 1);
        hl[u][c] = val;
    }
    __syncthreads();

    float acc[16];
    #pragma unroll
    for (int u = 0; u < 16; u++) acc[u] = 0.0f;

    for (int v = 0; v < VOC + 3; v++) {
        float m = M1[v * DIM + j];             // coalesced
        #pragma unroll
        for (int u = 0; u < 16; u++)
            acc[u] = fmaf(hl[u][v], m, acc[u]);  // LDS broadcast
    }

    float bj = b1[j];
    float wj = w2[j];
    float contrib[16];
    #pragma unroll
    for (int u = 0; u < 16; u++) {
        float pre = acc[u] / hl[u][103] + bj;
        contrib[u] = gelu_tanh(pre) * wj;
    }

    int wave = j >> 6;
    int lane = j & 63;
    #pragma unroll
    for (int u = 0; u < 16; u++) {
        float s = contrib[u];
        #pragma unroll
        for (int off = 32; off; off >>= 1) s += __shfl_down(s, off);
        if (lane == 0) part[wave][u] = s;
    }
    __syncthreads();

    if (j < 16) {
        int g = G0 + j;
        if (g < G) {
            float e = 0.0f;
            #pragma unroll
            for (int w = 0; w < 8; w++) e += part[w][j];
            out[g] = e + b2[0];
        }
    }
}

extern "C" void kernel_launch(void* const* d_in, const int* in_sizes, int n_in,
                              void* d_out, int out_size, void* d_ws, size_t ws_size,
                              hipStream_t stream) {
    const int*   an    = (const int*)d_in[0];
    const float* pos   = (const float*)d_in[1];
    const int*   batch = (const int*)d_in[2];
    const float* embed = (const float*)d_in[3];
    const float* w_pos = (const float*)d_in[4];
    const float* w1    = (const float*)d_in[5];
    const float* b1    = (const float*)d_in[6];
    const float* w2    = (const float*)d_in[7];
    const float* b2    = (const float*)d_in[8];
    float* out = (float*)d_out;

    const int n = in_sizes[0];       // 262144
    const int G = out_size;          // 4096

    char* ws = (char*)d_ws;
    const size_t HIST_B = (size_t)NGRAPH * VOC * 4;          // 1,638,400
    int*   hist   = (int*)ws;
    float* possum = (float*)(ws + HIST_B);
    int*   cnt    = (int*)(ws + HIST_B + (size_t)NGRAPH * 12);
    float* M1     = (float*)(ws + HIST_B + (size_t)NGRAPH * 16);

    // zero hist + possum + cnt (ws is poisoned 0xAA before every launch)
    hipMemsetAsync(d_ws, 0, HIST_B + (size_t)NGRAPH * 16, stream);

    // 1) per-atom accumulation
    int blocks = (n + 255) / 256;
    k_accum<<<blocks, 256, 0, stream>>>(an, pos, batch, hist, possum, cnt, n);

    // 2) M1 = concat(embed, w_pos) @ w1
    dim3 gmat(13, 4);
    k_mat<<<gmat, 128, 0, stream>>>(embed, w_pos, w1, M1);

    // 3) fused segment-mean-matmul + gelu + final dot
    int gb = (G + 15) / 16;
    k_final<<<gb, 512, 0, stream>>>(hist, possum, cnt, M1, b1, w2, b2, out, G);
}

// Round 7
// 169.450 us; speedup vs baseline: 1.5656x; 1.5656x over previous
//
#include <hip/hip_runtime.h>
#include <hip/hip_bf16.h>
#include <math.h>

// Problem constants (from reference)
#define NATOMS 262144
#define NGRAPH 4096
#define DIM    512
#define VOC    100
#define GPB    16      // graphs per block in k_accum

// Workspace layout (bytes):
//   hist   int32 [NGRAPH][VOC]  @ 0                     = 1,638,400
//   possum f32   [NGRAPH][3]    @ 1,638,400             =    49,152
//   cnt    int32 [NGRAPH]       @ 1,687,552             =    16,384
//   M1     f32   [103][512]     @ 1,703,936             =   210,944

__device__ __forceinline__ float gelu_tanh(float x) {
    // jax.nn.gelu default approximate=True (tanh form)
    const float c = 0.7978845608028654f; // sqrt(2/pi)
    float x3 = x * x * x;
    return 0.5f * x * (1.0f + tanhf(c * (x + 0.044715f * x3)));
}

__device__ __forceinline__ int lower_bound(const int* __restrict__ a, int n, int t) {
    int lo = 0, hi = n;
    while (lo < hi) {
        int mid = (lo + hi) >> 1;
        if (a[mid] < t) lo = mid + 1; else hi = mid;
    }
    return lo;
}

// Ownership-based per-atom accumulation: block b owns graphs [b*GPB, (b+1)*GPB).
// batch is sorted -> the block's atoms are a contiguous slice found by binary
// search. All accumulation in LDS; final write-out is non-atomic (exclusive
// ownership). ZERO global atomics.
__global__ void k_accum(const int* __restrict__ an, const float* __restrict__ pos,
                        const int* __restrict__ batch,
                        int* __restrict__ hist, float* __restrict__ possum,
                        int* __restrict__ cnt, int n) {
    const int g0 = blockIdx.x * GPB;
    const int t  = threadIdx.x;          // 0..255

    __shared__ int   lh[GPB][VOC];       // 6.4 KB
    __shared__ float lps[GPB][3];
    __shared__ int   lcnt[GPB];
    __shared__ int   range[2];

    // zero LDS accumulators
    for (int idx = t; idx < GPB * VOC; idx += 256) ((int*)lh)[idx] = 0;
    if (t < GPB * 3) ((float*)lps)[t] = 0.0f;
    if (t < GPB)     lcnt[t] = 0;
    if (t == 0) range[0] = lower_bound(batch, n, g0);
    if (t == 1) range[1] = lower_bound(batch, n, g0 + GPB);
    __syncthreads();

    const int lo = range[0], hi = range[1];

    for (int base = lo; base < hi; base += 256) {
        int i = base + t;
        bool act = (i < hi);
        int ic = act ? i : (hi - 1);     // clamped: defined g on every lane
        int g = batch[ic];
        int rel = g - g0;

        float px = 0.f, py = 0.f, pz = 0.f;
        int v = 0;
        if (act) {
            v  = an[i];
            px = pos[3 * i + 0];
            py = pos[3 * i + 1];
            pz = pos[3 * i + 2];
            atomicAdd(&lh[rel][v], 1);   // LDS atomic, spread addresses
        }

        int lane = t & 63;
        int gFirst = __shfl(g, 0);
        int gLast  = __shfl(g, 63);
        if (gFirst == gLast) {
            // wave-uniform graph: tree reduce, single LDS atomic per field
            float sx = px, sy = py, sz = pz;
            int   sc = act ? 1 : 0;
            #pragma unroll
            for (int off = 32; off; off >>= 1) {
                sx += __shfl_down(sx, off);
                sy += __shfl_down(sy, off);
                sz += __shfl_down(sz, off);
                sc += __shfl_down(sc, off);
            }
            if (lane == 0 && sc > 0) {
                atomicAdd(&lps[rel][0], sx);
                atomicAdd(&lps[rel][1], sy);
                atomicAdd(&lps[rel][2], sz);
                atomicAdd(&lcnt[rel], sc);
            }
        } else if (act) {
            atomicAdd(&lps[rel][0], px);
            atomicAdd(&lps[rel][1], py);
            atomicAdd(&lps[rel][2], pz);
            atomicAdd(&lcnt[rel], 1);
        }
    }
    __syncthreads();

    // exclusive write-out (no atomics)
    for (int idx = t; idx < GPB * VOC; idx += 256) {
        int u = idx / VOC, c = idx - u * VOC;
        hist[(g0 + u) * VOC + c] = lh[u][c];
    }
    if (t < GPB * 3) {
        int u = t / 3, c = t - u * 3;
        possum[(g0 + u) * 3 + c] = lps[u][c];
    }
    if (t < GPB) cnt[g0 + t] = lcnt[t];
}

// M1[103][512] = concat(embed[100][512], w_pos[3][512]) @ w1[512][512]
__global__ void k_mat(const float* __restrict__ embed, const float* __restrict__ w_pos,
                      const float* __restrict__ w1, float* __restrict__ M1) {
    int rt = blockIdx.x;           // 0..12 (row tile of 8)
    int jc = blockIdx.y;           // 0..3  (col chunk of 128)
    int t  = threadIdx.x;          // 0..127
    int j  = jc * 128 + t;
    int r0 = rt * 8;

    __shared__ float src[8][DIM];  // 16 KB
    for (int idx = t; idx < 8 * DIM; idx += 128) {
        int rr = idx >> 9;
        int k  = idx & (DIM - 1);
        int r  = r0 + rr;
        float val = 0.0f;
        if (r < VOC)          val = embed[r * DIM + k];
        else if (r < VOC + 3) val = w_pos[(r - VOC) * DIM + k];
        src[rr][k] = val;
    }
    __syncthreads();

    float acc[8];
    #pragma unroll
    for (int rr = 0; rr < 8; rr++) acc[rr] = 0.0f;

    #pragma unroll 4
    for (int k = 0; k < DIM; k++) {
        float w = w1[k * DIM + j];          // coalesced across threads
        #pragma unroll
        for (int rr = 0; rr < 8; rr++)
            acc[rr] = fmaf(src[rr][k], w, acc[rr]);  // src broadcast from LDS
    }

    #pragma unroll
    for (int rr = 0; rr < 8; rr++) {
        int r = r0 + rr;
        if (r < VOC + 3) M1[r * DIM + j] = acc[rr];
    }
}

// Final: per graph g: pre[j] = (hist[g]·M1[:,j]) / cnt + b1[j];
// energy[g] = sum_j gelu(pre[j]) * w2[j] + b2.
// 16 graphs per block, 512 threads (thread j owns output dim j).
__global__ void k_final(const int* __restrict__ hist, const float* __restrict__ possum,
                        const int* __restrict__ cnt, const float* __restrict__ M1,
                        const float* __restrict__ b1, const float* __restrict__ w2,
                        const float* __restrict__ b2, float* __restrict__ out, int G) {
    const int G0 = blockIdx.x * 16;
    const int j = threadIdx.x;                 // 0..511

    __shared__ float hl[16][104];              // [u][0..99]=hist, [100..102]=possum, [103]=count
    __shared__ float part[8][16];              // per-wave partials

    for (int idx = j; idx < 16 * 104; idx += 512) {
        int u = idx / 104;
        int c = idx - u * 104;
        int g = G0 + u;
        if (g >= G) g = G - 1;                 // safe dup (stores guarded below)
        float val;
        if (c < VOC)          val = (float)hist[g * VOC + c];
        else if (c < VOC + 3) val = possum[g * 3 + (c - VOC)];
        else                  val = fmaxf((float)cnt[g], 1.0f);
        hl[u][c] = val;
    }
    __syncthreads();

    float acc[16];
    #pragma unroll
    for (int u = 0; u < 16; u++) acc[u] = 0.0f;

    for (int v = 0; v < VOC + 3; v++) {
        float m = M1[v * DIM + j];             // coalesced
        #pragma unroll
        for (int u = 0; u < 16; u++)
            acc[u] = fmaf(hl[u][v], m, acc[u]);  // LDS broadcast
    }

    float bj = b1[j];
    float wj = w2[j];
    float contrib[16];
    #pragma unroll
    for (int u = 0; u < 16; u++) {
        float pre = acc[u] / hl[u][103] + bj;
        contrib[u] = gelu_tanh(pre) * wj;
    }

    int wave = j >> 6;
    int lane = j & 63;
    #pragma unroll
    for (int u = 0; u < 16; u++) {
        float s = contrib[u];
        #pragma unroll
        for (int off = 32; off; off >>= 1) s += __shfl_down(s, off);
        if (lane == 0) part[wave][u] = s;
    }
    __syncthreads();

    if (j < 16) {
        int g = G0 + j;
        if (g < G) {
            float e = 0.0f;
            #pragma unroll
            for (int w = 0; w < 8; w++) e += part[w][j];
            out[g] = e + b2[0];
        }
    }
}

extern "C" void kernel_launch(void* const* d_in, const int* in_sizes, int n_in,
                              void* d_out, int out_size, void* d_ws, size_t ws_size,
                              hipStream_t stream) {
    const int*   an    = (const int*)d_in[0];
    const float* pos   = (const float*)d_in[1];
    const int*   batch = (const int*)d_in[2];
    const float* embed = (const float*)d_in[3];
    const float* w_pos = (const float*)d_in[4];
    const float* w1    = (const float*)d_in[5];
    const float* b1    = (const float*)d_in[6];
    const float* w2    = (const float*)d_in[7];
    const float* b2    = (const float*)d_in[8];
    float* out = (float*)d_out;

    const int n = in_sizes[0];       // 262144
    const int G = out_size;          // 4096

    char* ws = (char*)d_ws;
    const size_t HIST_B = (size_t)NGRAPH * VOC * 4;          // 1,638,400
    int*   hist   = (int*)ws;
    float* possum = (float*)(ws + HIST_B);
    int*   cnt    = (int*)(ws + HIST_B + (size_t)NGRAPH * 12);
    float* M1     = (float*)(ws + HIST_B + (size_t)NGRAPH * 16);

    // 1) per-atom accumulation (ownership-based, no global atomics, no memset)
    k_accum<<<NGRAPH / GPB, 256, 0, stream>>>(an, pos, batch, hist, possum, cnt, n);

    // 2) M1 = concat(embed, w_pos) @ w1
    dim3 gmat(13, 4);
    k_mat<<<gmat, 128, 0, stream>>>(embed, w_pos, w1, M1);

    // 3) fused segment-mean-matmul + gelu + final dot
    int gb = (G + 15) / 16;
    k_final<<<gb, 512, 0, stream>>>(hist, possum, cnt, M1, b1, w2, b2, out, G);
}

// Round 8
// 122.458 us; speedup vs baseline: 2.1664x; 1.3837x over previous
//
#include <hip/hip_runtime.h>
#include <hip/hip_bf16.h>
#include <math.h>

// Problem constants (from reference)
#define NATOMS 262144
#define NGRAPH 4096
#define DIM    512
#define VOC    100
#define GPB    16      // graphs per block in accum path
#define KC     8       // K-split chunks for the S@w1 matmul
#define KLEN   (DIM / KC)   // 64
#define ROWS   104     // 103 rows padded to 104

// Workspace layout (bytes):
//   hist    int32 [NGRAPH][VOC]   @ 0          = 1,638,400
//   possum  f32   [NGRAPH][3]     @ 1,638,400  =    49,152
//   cnt     int32 [NGRAPH]        @ 1,687,552  =    16,384
//   M1      f32   [103][512]      @ 1,703,936  =   210,944
//   partial f32   [KC][104][512]  @ 1,914,880  = 1,703,936
// total 3,618,816 B

__device__ __forceinline__ float gelu_tanh(float x) {
    const float c = 0.7978845608028654f; // sqrt(2/pi)
    float x3 = x * x * x;
    return 0.5f * x * (1.0f + tanhf(c * (x + 0.044715f * x3)));
}

__device__ __forceinline__ int lower_bound(const int* __restrict__ a, int n, int t) {
    int lo = 0, hi = n;
    while (lo < hi) {
        int mid = (lo + hi) >> 1;
        if (a[mid] < t) lo = mid + 1; else hi = mid;
    }
    return lo;
}

// Fused: blocks [0,256) do ownership-based per-atom accumulation (zero global
// atomics); blocks [256,464) compute split-K partials of
// M1 = concat(embed,w_pos) @ w1. The two halves touch disjoint data, so the
// small matmul hides entirely under the atom pass.
__global__ void k_fused(const int* __restrict__ an, const float* __restrict__ pos,
                        const int* __restrict__ batch,
                        const float* __restrict__ embed, const float* __restrict__ w_pos,
                        const float* __restrict__ w1,
                        int* __restrict__ hist, float* __restrict__ possum,
                        int* __restrict__ cnt, float* __restrict__ partial, int n) {
    const int t = threadIdx.x;           // 0..255

    if (blockIdx.x < NGRAPH / GPB) {
        // ---------------- accum path (256 blocks) ----------------
        const int g0 = blockIdx.x * GPB;

        __shared__ int   lh[GPB][VOC];   // 6.4 KB
        __shared__ float lps[GPB][3];
        __shared__ int   lcnt[GPB];
        __shared__ int   range[2];

        for (int idx = t; idx < GPB * VOC; idx += 256) ((int*)lh)[idx] = 0;
        if (t < GPB * 3) ((float*)lps)[t] = 0.0f;
        if (t < GPB)     lcnt[t] = 0;
        if (t == 0) range[0] = lower_bound(batch, n, g0);
        if (t == 1) range[1] = lower_bound(batch, n, g0 + GPB);
        __syncthreads();

        const int lo = range[0], hi = range[1];

        for (int base = lo; base < hi; base += 256) {
            int i = base + t;
            bool act = (i < hi);
            int ic = act ? i : (hi - 1);     // clamped: defined g on every lane
            int g = batch[ic];
            int rel = g - g0;

            float px = 0.f, py = 0.f, pz = 0.f;
            if (act) {
                int v = an[i];
                px = pos[3 * i + 0];
                py = pos[3 * i + 1];
                pz = pos[3 * i + 2];
                atomicAdd(&lh[rel][v], 1);   // LDS atomic, spread addresses
            }

            int lane = t & 63;
            int gFirst = __shfl(g, 0);
            int gLast  = __shfl(g, 63);
            if (gFirst == gLast) {
                float sx = px, sy = py, sz = pz;
                int   sc = act ? 1 : 0;
                #pragma unroll
                for (int off = 32; off; off >>= 1) {
                    sx += __shfl_down(sx, off);
                    sy += __shfl_down(sy, off);
                    sz += __shfl_down(sz, off);
                    sc += __shfl_down(sc, off);
                }
                if (lane == 0 && sc > 0) {
                    atomicAdd(&lps[rel][0], sx);
                    atomicAdd(&lps[rel][1], sy);
                    atomicAdd(&lps[rel][2], sz);
                    atomicAdd(&lcnt[rel], sc);
                }
            } else if (act) {
                atomicAdd(&lps[rel][0], px);
                atomicAdd(&lps[rel][1], py);
                atomicAdd(&lps[rel][2], pz);
                atomicAdd(&lcnt[rel], 1);
            }
        }
        __syncthreads();

        for (int idx = t; idx < GPB * VOC; idx += 256) {
            int u = idx / VOC, c = idx - u * VOC;
            hist[(g0 + u) * VOC + c] = lh[u][c];
        }
        if (t < GPB * 3) {
            int u = t / 3, c = t - u * 3;
            possum[(g0 + u) * 3 + c] = lps[u][c];
        }
        if (t < GPB) cnt[g0 + t] = lcnt[t];
    } else {
        // ---------------- mat-partial path (208 blocks) ----------------
        // mb -> (kc, rt, cc): 13 row-tiles x 2 col-chunks x 8 K-chunks
        const int mb = blockIdx.x - NGRAPH / GPB;
        const int kc = mb & (KC - 1);        // 0..7
        const int rc = mb >> 3;              // 0..25
        const int rt = rc >> 1;              // 0..12
        const int cc = rc & 1;               // 0..1
        const int j  = cc * 256 + t;
        const int r0 = rt * 8;
        const int k0 = kc * KLEN;

        __shared__ float s[8][KLEN];         // 2 KB
        for (int idx = t; idx < 8 * KLEN; idx += 256) {
            int rr = idx / KLEN, k = idx & (KLEN - 1);
            int r = r0 + rr;
            float val = 0.0f;
            if (r < VOC)          val = embed[r * DIM + k0 + k];
            else if (r < VOC + 3) val = w_pos[(r - VOC) * DIM + k0 + k];
            s[rr][k] = val;
        }
        __syncthreads();

        float acc[8];
        #pragma unroll
        for (int rr = 0; rr < 8; rr++) acc[rr] = 0.0f;

        #pragma unroll 8
        for (int k = 0; k < KLEN; k++) {
            float w = w1[(k0 + k) * DIM + j];    // coalesced; 8 in flight
            #pragma unroll
            for (int rr = 0; rr < 8; rr++)
                acc[rr] = fmaf(s[rr][k], w, acc[rr]);   // LDS broadcast
        }

        #pragma unroll
        for (int rr = 0; rr < 8; rr++)
            partial[((size_t)kc * ROWS + r0 + rr) * DIM + j] = acc[rr];
    }
}

// M1[r][j] = sum_kc partial[kc][r][j]
__global__ void k_reduce(const float* __restrict__ partial, float* __restrict__ M1) {
    int idx = blockIdx.x * 256 + threadIdx.x;
    if (idx >= 103 * DIM) return;
    int r = idx / DIM, j = idx - r * DIM;
    float sum = 0.0f;
    #pragma unroll
    for (int kc = 0; kc < KC; kc++)
        sum += partial[((size_t)kc * ROWS + r) * DIM + j];
    M1[r * DIM + j] = sum;
}

// ---------------- legacy fallback (ws too small for partials) ----------------
__global__ void k_accum(const int* __restrict__ an, const float* __restrict__ pos,
                        const int* __restrict__ batch,
                        int* __restrict__ hist, float* __restrict__ possum,
                        int* __restrict__ cnt, int n) {
    const int g0 = blockIdx.x * GPB;
    const int t  = threadIdx.x;

    __shared__ int   lh[GPB][VOC];
    __shared__ float lps[GPB][3];
    __shared__ int   lcnt[GPB];
    __shared__ int   range[2];

    for (int idx = t; idx < GPB * VOC; idx += 256) ((int*)lh)[idx] = 0;
    if (t < GPB * 3) ((float*)lps)[t] = 0.0f;
    if (t < GPB)     lcnt[t] = 0;
    if (t == 0) range[0] = lower_bound(batch, n, g0);
    if (t == 1) range[1] = lower_bound(batch, n, g0 + GPB);
    __syncthreads();

    const int lo = range[0], hi = range[1];
    for (int base = lo; base < hi; base += 256) {
        int i = base + t;
        bool act = (i < hi);
        int ic = act ? i : (hi - 1);
        int g = batch[ic];
        int rel = g - g0;
        float px = 0.f, py = 0.f, pz = 0.f;
        if (act) {
            int v = an[i];
            px = pos[3 * i];
            py = pos[3 * i + 1];
            pz = pos[3 * i + 2];
            atomicAdd(&lh[rel][v], 1);
        }
        int lane = t & 63;
        int gFirst = __shfl(g, 0);
        int gLast  = __shfl(g, 63);
        if (gFirst == gLast) {
            float sx = px, sy = py, sz = pz;
            int sc = act ? 1 : 0;
            #pragma unroll
            for (int off = 32; off; off >>= 1) {
                sx += __shfl_down(sx, off);
                sy += __shfl_down(sy, off);
                sz += __shfl_down(sz, off);
                sc += __shfl_down(sc, off);
            }
            if (lane == 0 && sc > 0) {
                atomicAdd(&lps[rel][0], sx);
                atomicAdd(&lps[rel][1], sy);
                atomicAdd(&lps[rel][2], sz);
                atomicAdd(&lcnt[rel], sc);
            }
        } else if (act) {
            atomicAdd(&lps[rel][0], px);
            atomicAdd(&lps[rel][1], py);
            atomicAdd(&lps[rel][2], pz);
            atomicAdd(&lcnt[rel], 1);
        }
    }
    __syncthreads();

    for (int idx = t; idx < GPB * VOC; idx += 256) {
        int u = idx / VOC, c = idx - u * VOC;
        hist[(g0 + u) * VOC + c] = lh[u][c];
    }
    if (t < GPB * 3) {
        int u = t / 3, c = t - u * 3;
        possum[(g0 + u) * 3 + c] = lps[u][c];
    }
    if (t < GPB) cnt[g0 + t] = lcnt[t];
}

__global__ void k_mat(const float* __restrict__ embed, const float* __restrict__ w_pos,
                      const float* __restrict__ w1, float* __restrict__ M1) {
    int rt = blockIdx.x, jc = blockIdx.y, t = threadIdx.x;
    int j = jc * 128 + t;
    int r0 = rt * 8;
    __shared__ float src[8][DIM];
    for (int idx = t; idx < 8 * DIM; idx += 128) {
        int rr = idx >> 9, k = idx & (DIM - 1);
        int r = r0 + rr;
        float val = 0.0f;
        if (r < VOC)          val = embed[r * DIM + k];
        else if (r < VOC + 3) val = w_pos[(r - VOC) * DIM + k];
        src[rr][k] = val;
    }
    __syncthreads();
    float acc[8];
    #pragma unroll
    for (int rr = 0; rr < 8; rr++) acc[rr] = 0.0f;
    #pragma unroll 4
    for (int k = 0; k < DIM; k++) {
        float w = w1[k * DIM + j];
        #pragma unroll
        for (int rr = 0; rr < 8; rr++)
            acc[rr] = fmaf(src[rr][k], w, acc[rr]);
    }
    #pragma unroll
    for (int rr = 0; rr < 8; rr++) {
        int r = r0 + rr;
        if (r < VOC + 3) M1[r * DIM + j] = acc[rr];
    }
}

// Final: per graph g: pre[j] = (hist[g]·M1[:,j]) / cnt + b1[j];
// energy[g] = sum_j gelu(pre[j]) * w2[j] + b2.
__global__ void k_final(const int* __restrict__ hist, const float* __restrict__ possum,
                        const int* __restrict__ cnt, const float* __restrict__ M1,
                        const float* __restrict__ b1, const float* __restrict__ w2,
                        const float* __restrict__ b2, float* __restrict__ out, int G) {
    const int G0 = blockIdx.x * 16;
    const int j = threadIdx.x;                 // 0..511

    __shared__ float hl[16][104];
    __shared__ float part[8][16];

    for (int idx = j; idx < 16 * 104; idx += 512) {
        int u = idx / 104;
        int c = idx - u * 104;
        int g = G0 + u;
        if (g >= G) g = G - 1;
        float val;
        if (c < VOC)          val = (float)hist[g * VOC + c];
        else if (c < VOC + 3) val = possum[g * 3 + (c - VOC)];
        else                  val = fmaxf((float)cnt[g], 1.0f);
        hl[u][c] = val;
    }
    __syncthreads();

    float acc[16];
    #pragma unroll
    for (int u = 0; u < 16; u++) acc[u] = 0.0f;

    for (int v = 0; v < VOC + 3; v++) {
        float m = M1[v * DIM + j];             // coalesced
        #pragma unroll
        for (int u = 0; u < 16; u++)
            acc[u] = fmaf(hl[u][v], m, acc[u]);  // LDS broadcast
    }

    float bj = b1[j];
    float wj = w2[j];
    float contrib[16];
    #pragma unroll
    for (int u = 0; u < 16; u++) {
        float pre = acc[u] / hl[u][103] + bj;
        contrib[u] = gelu_tanh(pre) * wj;
    }

    int wave = j >> 6;
    int lane = j & 63;
    #pragma unroll
    for (int u = 0; u < 16; u++) {
        float s = contrib[u];
        #pragma unroll
        for (int off = 32; off; off >>= 1) s += __shfl_down(s, off);
        if (lane == 0) part[wave][u] = s;
    }
    __syncthreads();

    if (j < 16) {
        int g = G0 + j;
        if (g < G) {
            float e = 0.0f;
            #pragma unroll
            for (int w = 0; w < 8; w++) e += part[w][j];
            out[g] = e + b2[0];
        }
    }
}

extern "C" void kernel_launch(void* const* d_in, const int* in_sizes, int n_in,
                              void* d_out, int out_size, void* d_ws, size_t ws_size,
                              hipStream_t stream) {
    const int*   an    = (const int*)d_in[0];
    const float* pos   = (const float*)d_in[1];
    const int*   batch = (const int*)d_in[2];
    const float* embed = (const float*)d_in[3];
    const float* w_pos = (const float*)d_in[4];
    const float* w1    = (const float*)d_in[5];
    const float* b1    = (const float*)d_in[6];
    const float* w2    = (const float*)d_in[7];
    const float* b2    = (const float*)d_in[8];
    float* out = (float*)d_out;

    const int n = in_sizes[0];       // 262144
    const int G = out_size;          // 4096

    char* ws = (char*)d_ws;
    const size_t HIST_B = (size_t)NGRAPH * VOC * 4;          // 1,638,400
    int*   hist    = (int*)ws;
    float* possum  = (float*)(ws + HIST_B);
    int*   cnt     = (int*)(ws + HIST_B + (size_t)NGRAPH * 12);
    float* M1      = (float*)(ws + HIST_B + (size_t)NGRAPH * 16);
    float* partial = (float*)(ws + HIST_B + (size_t)NGRAPH * 16 + (size_t)103 * DIM * 4);

    const size_t NEED = HIST_B + (size_t)NGRAPH * 16 + (size_t)103 * DIM * 4
                      + (size_t)KC * ROWS * DIM * 4;         // 3,618,816

    if (ws_size >= NEED) {
        // 1) fused accum + split-K mat partials (464 blocks)
        const int AB = NGRAPH / GPB;                 // 256
        const int MB = 13 * 2 * KC;                  // 208
        k_fused<<<AB + MB, 256, 0, stream>>>(an, pos, batch, embed, w_pos, w1,
                                             hist, possum, cnt, partial, n);
        // 2) reduce partials -> M1
        k_reduce<<<(103 * DIM + 255) / 256, 256, 0, stream>>>(partial, M1);
    } else {
        // legacy path (measured-correct in R7)
        k_accum<<<NGRAPH / GPB, 256, 0, stream>>>(an, pos, batch, hist, possum, cnt, n);
        dim3 gmat(13, 4);
        k_mat<<<gmat, 128, 0, stream>>>(embed, w_pos, w1, M1);
    }

    // 3) fused segment-mean-matmul + gelu + final dot
    int gb = (G + 15) / 16;
    k_final<<<gb, 512, 0, stream>>>(hist, possum, cnt, M1, b1, w2, b2, out, G);
}

// Round 11
// 111.520 us; speedup vs baseline: 2.3789x; 1.0981x over previous
//
#include <hip/hip_runtime.h>
#include <hip/hip_bf16.h>
#include <math.h>

// Problem constants (from reference)
#define NATOMS 262144
#define NGRAPH 4096
#define DIM    512
#define VOC    100
#define GPB    16          // graphs per block in accum path
#define KC     8           // K-split chunks for the S@w1 matmul
#define KLEN   (DIM / KC)  // 64
#define ROWS   104         // 103 rows padded to 104
#define HROW   104         // Hf row stride (floats)

// Workspace layout (bytes):
//   Hf      f32 [NGRAPH][104]   @ 0          = 1,703,936   (mean-applied features)
//   M1      f32 [103][512]      @ 1,703,936  =   210,944
//   partial f32 [KC][104][512]  @ 1,914,880  = 1,703,936
// total 3,618,816 B  (ws measured ~268 MB)

__device__ __forceinline__ float gelu_tanh(float x) {
    const float c = 0.7978845608028654f; // sqrt(2/pi)
    float x3 = x * x * x;
    return 0.5f * x * (1.0f + tanhf(c * (x + 0.044715f * x3)));
}

__device__ __forceinline__ int lower_bound(const int* __restrict__ a, int n, int t) {
    int lo = 0, hi = n;
    while (lo < hi) {
        int mid = (lo + hi) >> 1;
        if (a[mid] < t) lo = mid + 1; else hi = mid;
    }
    return lo;
}

// Fused: blocks [0,256) do ownership-based per-atom accumulation (zero global
// atomics), writing mean-applied float features Hf; blocks [256,464) compute
// split-K partials of M1 = concat(embed,w_pos) @ w1. Disjoint data; the small
// matmul hides under the atom pass.
__global__ void k_fused(const int* __restrict__ an, const float* __restrict__ pos,
                        const int* __restrict__ batch,
                        const float* __restrict__ embed, const float* __restrict__ w_pos,
                        const float* __restrict__ w1,
                        float* __restrict__ Hf, float* __restrict__ partial, int n) {
    const int t = threadIdx.x;           // 0..255

    if (blockIdx.x < NGRAPH / GPB) {
        // ---------------- accum path (256 blocks) ----------------
        const int g0 = blockIdx.x * GPB;

        __shared__ int   lh[GPB][VOC];   // 6.4 KB
        __shared__ float lps[GPB][3];
        __shared__ int   lcnt[GPB];
        __shared__ int   range[2];

        for (int idx = t; idx < GPB * VOC; idx += 256) ((int*)lh)[idx] = 0;
        if (t < GPB * 3) ((float*)lps)[t] = 0.0f;
        if (t < GPB)     lcnt[t] = 0;
        if (t == 0) range[0] = lower_bound(batch, n, g0);
        if (t == 1) range[1] = lower_bound(batch, n, g0 + GPB);
        __syncthreads();

        const int lo = range[0], hi = range[1];

        for (int base = lo; base < hi; base += 256) {
            int i = base + t;
            bool act = (i < hi);
            int ic = act ? i : (hi - 1);     // clamped: defined g on every lane
            int g = batch[ic];
            int rel = g - g0;

            float px = 0.f, py = 0.f, pz = 0.f;
            if (act) {
                int v = an[i];
                px = pos[3 * i + 0];
                py = pos[3 * i + 1];
                pz = pos[3 * i + 2];
                atomicAdd(&lh[rel][v], 1);   // LDS atomic, spread addresses
            }

            int lane = t & 63;
            int gFirst = __shfl(g, 0);
            int gLast  = __shfl(g, 63);
            if (gFirst == gLast) {
                float sx = px, sy = py, sz = pz;
                int   sc = act ? 1 : 0;
                #pragma unroll
                for (int off = 32; off; off >>= 1) {
                    sx += __shfl_down(sx, off);
                    sy += __shfl_down(sy, off);
                    sz += __shfl_down(sz, off);
                    sc += __shfl_down(sc, off);
                }
                if (lane == 0 && sc > 0) {
                    atomicAdd(&lps[rel][0], sx);
                    atomicAdd(&lps[rel][1], sy);
                    atomicAdd(&lps[rel][2], sz);
                    atomicAdd(&lcnt[rel], sc);
                }
            } else if (act) {
                atomicAdd(&lps[rel][0], px);
                atomicAdd(&lps[rel][1], py);
                atomicAdd(&lps[rel][2], pz);
                atomicAdd(&lcnt[rel], 1);
            }
        }
        __syncthreads();

        // exclusive write-out, mean pre-applied (no atomics)
        for (int idx = t; idx < GPB * HROW; idx += 256) {
            int u = idx / HROW, c = idx - u * HROW;
            float inv = 1.0f / fmaxf((float)lcnt[u], 1.0f);
            float val = 0.0f;
            if (c < VOC)          val = (float)lh[u][c] * inv;
            else if (c < VOC + 3) val = lps[u][c - VOC] * inv;
            Hf[(size_t)(g0 + u) * HROW + c] = val;
        }
    } else {
        // ---------------- mat-partial path (208 blocks) ----------------
        const int mb = blockIdx.x - NGRAPH / GPB;
        const int kc = mb & (KC - 1);        // 0..7
        const int rc = mb >> 3;              // 0..25
        const int rt = rc >> 1;              // 0..12
        const int cc = rc & 1;               // 0..1
        const int j  = cc * 256 + t;
        const int r0 = rt * 8;
        const int k0 = kc * KLEN;

        __shared__ float s[8][KLEN];         // 2 KB
        for (int idx = t; idx < 8 * KLEN; idx += 256) {
            int rr = idx / KLEN, k = idx & (KLEN - 1);
            int r = r0 + rr;
            float val = 0.0f;
            if (r < VOC)          val = embed[r * DIM + k0 + k];
            else if (r < VOC + 3) val = w_pos[(r - VOC) * DIM + k0 + k];
            s[rr][k] = val;
        }
        __syncthreads();

        float acc[8];
        #pragma unroll
        for (int rr = 0; rr < 8; rr++) acc[rr] = 0.0f;

        #pragma unroll 8
        for (int k = 0; k < KLEN; k++) {
            float w = w1[(k0 + k) * DIM + j];    // coalesced; 8 in flight
            #pragma unroll
            for (int rr = 0; rr < 8; rr++)
                acc[rr] = fmaf(s[rr][k], w, acc[rr]);   // LDS broadcast
        }

        #pragma unroll
        for (int rr = 0; rr < 8; rr++)
            partial[((size_t)kc * ROWS + r0 + rr) * DIM + j] = acc[rr];
    }
}

// M1[r][j] = sum_kc partial[kc][r][j]
__global__ void k_reduce(const float* __restrict__ partial, float* __restrict__ M1) {
    int idx = blockIdx.x * 256 + threadIdx.x;
    if (idx >= 103 * DIM) return;
    int r = idx / DIM, j = idx - r * DIM;
    float sum = 0.0f;
    #pragma unroll
    for (int kc = 0; kc < KC; kc++)
        sum += partial[((size_t)kc * ROWS + r) * DIM + j];
    M1[r * DIM + j] = sum;
}

// Final: per graph g: pre[j] = Hf[g]·M1[:,j] + b1[j];
// energy[g] = sum_j gelu(pre[j]) * w2[j] + b2.
// 16 graphs per block, 512 threads (thread j owns output dim j).
// Hf rows staged TRANSPOSED in LDS (hT[v][u], 80B padded rows) so the hot
// loop does 4x ds_read_b128 broadcast per v instead of 16x ds_read_b32.
__global__ void k_final(const float* __restrict__ Hf, const float* __restrict__ M1,
                        const float* __restrict__ b1, const float* __restrict__ w2,
                        const float* __restrict__ b2, float* __restrict__ out) {
    const int G0 = blockIdx.x * 16;
    const int j = threadIdx.x;                 // 0..511

    __shared__ float hT[HROW][20];             // [v][u], 20-float rows: 16B-aligned
    __shared__ float part[8][16];              // per-wave partials

    for (int idx = j; idx < 16 * HROW; idx += 512) {
        int u = idx / HROW;                    // 0..15
        int v = idx - u * HROW;                // 0..103  (coalesced global read)
        hT[v][u] = Hf[(size_t)(G0 + u) * HROW + v];
    }
    __syncthreads();

    float acc[16];
    #pragma unroll
    for (int u = 0; u < 16; u++) acc[u] = 0.0f;

    for (int v = 0; v < VOC + 3; v++) {
        float m = M1[v * DIM + j];             // coalesced, L2-resident
        const float4* hp = (const float4*)(&hT[v][0]);
        float4 h0 = hp[0], h1 = hp[1], h2 = hp[2], h3 = hp[3];  // broadcast b128
        acc[ 0] = fmaf(h0.x, m, acc[ 0]);
        acc[ 1] = fmaf(h0.y, m, acc[ 1]);
        acc[ 2] = fmaf(h0.z, m, acc[ 2]);
        acc[ 3] = fmaf(h0.w, m, acc[ 3]);
        acc[ 4] = fmaf(h1.x, m, acc[ 4]);
        acc[ 5] = fmaf(h1.y, m, acc[ 5]);
        acc[ 6] = fmaf(h1.z, m, acc[ 6]);
        acc[ 7] = fmaf(h1.w, m, acc[ 7]);
        acc[ 8] = fmaf(h2.x, m, acc[ 8]);
        acc[ 9] = fmaf(h2.y, m, acc[ 9]);
        acc[10] = fmaf(h2.z, m, acc[10]);
        acc[11] = fmaf(h2.w, m, acc[11]);
        acc[12] = fmaf(h3.x, m, acc[12]);
        acc[13] = fmaf(h3.y, m, acc[13]);
        acc[14] = fmaf(h3.z, m, acc[14]);
        acc[15] = fmaf(h3.w, m, acc[15]);
    }

    float bj = b1[j];
    float wj = w2[j];
    float contrib[16];
    #pragma unroll
    for (int u = 0; u < 16; u++) {
        float pre = acc[u] + bj;               // mean already applied in Hf
        contrib[u] = gelu_tanh(pre) * wj;
    }

    int wave = j >> 6;
    int lane = j & 63;
    #pragma unroll
    for (int u = 0; u < 16; u++) {
        float s = contrib[u];
        #pragma unroll
        for (int off = 32; off; off >>= 1) s += __shfl_down(s, off);
        if (lane == 0) part[wave][u] = s;
    }
    __syncthreads();

    if (j < 16) {
        float e = 0.0f;
        #pragma unroll
        for (int w = 0; w < 8; w++) e += part[w][j];
        out[G0 + j] = e + b2[0];
    }
}

extern "C" void kernel_launch(void* const* d_in, const int* in_sizes, int n_in,
                              void* d_out, int out_size, void* d_ws, size_t ws_size,
                              hipStream_t stream) {
    const int*   an    = (const int*)d_in[0];
    const float* pos   = (const float*)d_in[1];
    const int*   batch = (const int*)d_in[2];
    const float* embed = (const float*)d_in[3];
    const float* w_pos = (const float*)d_in[4];
    const float* w1    = (const float*)d_in[5];
    const float* b1    = (const float*)d_in[6];
    const float* w2    = (const float*)d_in[7];
    const float* b2    = (const float*)d_in[8];
    float* out = (float*)d_out;

    const int n = in_sizes[0];       // 262144

    char* ws = (char*)d_ws;
    const size_t HF_B = (size_t)NGRAPH * HROW * 4;           // 1,703,936
    const size_t M1_B = (size_t)103 * DIM * 4;               //   210,944
    float* Hf      = (float*)ws;
    float* M1      = (float*)(ws + HF_B);
    float* partial = (float*)(ws + HF_B + M1_B);

    // 1) fused accum (mean-applied Hf) + split-K mat partials (464 blocks)
    const int AB = NGRAPH / GPB;                 // 256
    const int MB = 13 * 2 * KC;                  // 208
    k_fused<<<AB + MB, 256, 0, stream>>>(an, pos, batch, embed, w_pos, w1,
                                         Hf, partial, n);
    // 2) reduce partials -> M1
    k_reduce<<<(103 * DIM + 255) / 256, 256, 0, stream>>>(partial, M1);

    // 3) fused mean-matmul + gelu + final dot
    k_final<<<NGRAPH / 16, 512, 0, stream>>>(Hf, M1, b1, w2, b2, out);
}